// Round 5
// baseline (124957.654 us; speedup 1.0000x reference)
//
#include <hip/hip_runtime.h>
#include <hip/hip_bf16.h>

typedef __hip_bfloat16 bf16;
typedef unsigned long long u64;

#define NSTEP 1024
#define BATCH 64
#define HID   512
#define GRID  256
#define NTHR  512

// ---- workspace layout (bytes) ----
// barrier block [0,1024): global@0, xcd[x]@64+64x (x=0..7), rel@576, flag@640
#define OFF_BAR   0u
#define OFF_FLAG  640u
#define OFF_HG    1024u
#define OFF_CG    132096u
#define OFF_GALL  263168u
#define OFF_UCAT  2884608u
#define OFF_WA    23856128u
#define OFF_WM    24904704u
#define OFF_WX    25166848u
#define OFF_BM    25265152u
#define OFF_BX    25273344u
#define OFF_BA    25306112u
#define OFF_YT    25308160u
#define OFF_XT    33696768u

// ---- LDS carve (float indices) ----
// persistent: US[40][524], WML[40][36], HA[4][64][36]
// overlay A : YA[64][36], XA[8][64][3], GB[64][40]; REDA in dead HA zone
// overlay B : LB[9][520] over YA/XA/GB head; RA/RB/MPZ in dead HA zone
#define L_US    0         /* 40*524 = 20960 */
#define L_WML   20960     /* 40*36 = 1440 -> 22400 */
#define L_HA    22400     /* 4*2304 = 9216 -> 31616 */
#define L_YA    31616     /* 64*36 = 2304 -> 33920 */
#define L_XA    33920     /* 1536 -> 35456 */
#define L_GB    35456     /* 2560 -> 38016 */
#define L_REDA  22400     /* phase A red: 384*22 = 8448 (HA dead) */
#define L_LB    31616     /* phase B: 9*520 = 4680 -> 36296 (YA/XA/GB dead) */
#define L_RA    22400     /* phase B hop A: 256*19 = 4864 */
#define L_RB    27264     /* phase B hop B: 128*19 = 2432 -> 29696 */
#define L_MPZ   29696     /* phase B final m: 64*19 = 1216 -> 30912 */
#define L_TOT   38016     /* 152064 B < 160 KB */

#define US(c,k)    smem[L_US  + (c)*524 + (k)]
#define WML(c,j)   smem[L_WML + (c)*36  + (j)]
#define HA(q,b,k)  smem[L_HA  + (q)*2304 + (b)*36 + (k)]
#define YA(b,j)    smem[L_YA  + (b)*36 + (j)]
#define XA(a,b,j)  smem[L_XA  + ((a)*64 + (b))*3 + (j)]
#define GB(r,c)    smem[L_GB  + (r)*40 + (c)]
#define LB(j,h)    smem[L_LB  + (j)*520 + (h)]

struct RawIn {
  const void *Y, *x[8];
  const void *W_i,*U_i,*b_i, *W_f,*U_f,*b_f, *W_c,*U_c,*b_c, *W_o,*U_o,*b_o;
  const void *W_ix,*U_ix,*b_ix, *W_cx,*U_cx,*b_cx, *W_a,*b_a;
  float *Ucat,*Wa,*Wm,*Wx,*Bm,*Bx,*Ba,*Yt,*Xt;
  const unsigned *flag;
};

struct Params {
  const float *Ucat,*Wa,*Wm,*Wx,*Bm,*Bx,*Ba,*Yt,*Xt;
  float *Hg,*Cg,*Gall;
  unsigned *bar;
  const unsigned *flag;
  void *out;
};

// ---------------- dtype probe -------------------------------------------------
__global__ void k_detect(const unsigned short* __restrict__ p, unsigned* flag) {
  if (blockIdx.x == 0 && threadIdx.x == 0) {
    int cnt = 0;
    for (int i = 0; i < 64; ++i) {
      unsigned e = (p[i] >> 7) & 0xFF;
      cnt += (e >= 0x60 && e <= 0x7C) || (p[i] & 0x7FFF) == 0;
    }
    *flag = (cnt >= 56) ? 1u : 0u;   // 1 = bf16, 0 = fp32
  }
}

__device__ __forceinline__ float cvt(const void* p, size_t i, bool bf) {
  return bf ? (float)((const bf16*)p)[i] : ((const float*)p)[i];
}

// ---------------- weight normalization ---------------------------------------
#define NWTOT 5605888
__global__ __launch_bounds__(256)
void k_conv_w(RawIn R) {
  const bool bf = (*R.flag) != 0;
  for (size_t i = blockIdx.x*256 + threadIdx.x; i < NWTOT; i += (size_t)gridDim.x*256) {
    if (i < 5242880) {           // Ucat [20][512][512]
      size_t g = i >> 18, r = i & 262143;
      const void* s = g<4 ? (g==0?R.U_i:g==1?R.U_f:g==2?R.U_c:R.U_o)
                    : g<12 ? R.U_ix : R.U_cx;
      size_t off = g<4 ? r : g<12 ? (g-4)*262144 + r : (g-12)*262144 + r;
      R.Ucat[i] = cvt(s, off, bf);
    } else {
      size_t j = i - 5242880;
      if (j < 262144) { R.Wa[j] = cvt(R.W_a, j, bf); }
      else {
        size_t j2 = j - 262144;
        if (j2 < 65536) {        // Wm [4][32][512]
          size_t g = j2 >> 14, r = j2 & 16383;
          const void* s = g==0?R.W_i:g==1?R.W_f:g==2?R.W_c:R.W_o;
          R.Wm[j2] = cvt(s, r, bf);
        } else {
          size_t j3 = j2 - 65536;
          if (j3 < 24576) {      // Wx [16][3][512]
            size_t p = j3 / 1536, r = j3 % 1536;
            R.Wx[j3] = p < 8 ? cvt(R.W_ix, p*1536 + r, bf)
                             : cvt(R.W_cx, (p-8)*1536 + r, bf);
          } else {
            size_t j4 = j3 - 24576;
            if (j4 < 2048) {     // Bm [4][512]
              size_t g = j4 >> 9, c = j4 & 511;
              const void* s = g==0?R.b_i:g==1?R.b_f:g==2?R.b_c:R.b_o;
              R.Bm[j4] = cvt(s, c, bf);
            } else {
              size_t j5 = j4 - 2048;
              if (j5 < 8192) {   // Bx [16][512]
                size_t p = j5 >> 9, c = j5 & 511;
                R.Bx[j5] = p < 8 ? cvt(R.b_ix, p*512 + c, bf)
                                 : cvt(R.b_cx, (p-8)*512 + c, bf);
              } else {
                size_t j6 = j5 - 8192;       // Ba [512]
                R.Ba[j6] = cvt(R.b_a, j6, bf);
              }
            }
          }
        }
      }
    }
  }
}

// ---------------- input normalization (time-major pack) -----------------------
#define NYT 2097152
#define NXT 1572864
__global__ __launch_bounds__(256)
void k_conv_in(RawIn R) {
  const bool bf = (*R.flag) != 0;
  for (size_t i = blockIdx.x*256 + threadIdx.x; i < NYT+NXT; i += (size_t)gridDim.x*256) {
    if (i < NYT) {               // Yt [t][b][32]
      size_t j = i & 31, b = (i >> 5) & 63, t = i >> 11;
      R.Yt[i] = cvt(R.Y, (b*32 + j)*NSTEP + t, bf);
    } else {                     // Xt [t][8][b][3]
      size_t i2 = i - NYT;
      size_t j = i2 % 3, r = i2 / 3;
      size_t b = r & 63; r >>= 6;
      size_t a = r & 7, t = r >> 3;
      R.Xt[i2] = cvt(R.x[a], (b*3 + j)*NSTEP + t, bf);
    }
  }
}

// ---------------- helpers -----------------------------------------------------

__device__ __forceinline__ float sigf(float v){ return 1.f/(1.f+expf(-v)); }

__device__ __forceinline__ float gload(const float* p){
  return __hip_atomic_load(p, __ATOMIC_RELAXED, __HIP_MEMORY_SCOPE_AGENT);
}
__device__ __forceinline__ u64 gload2(const float* p){
  return __hip_atomic_load((const u64*)p, __ATOMIC_RELAXED, __HIP_MEMORY_SCOPE_AGENT);
}
__device__ __forceinline__ void gstore(float* p, float v){
  __hip_atomic_store(p, v, __ATOMIC_RELAXED, __HIP_MEMORY_SCOPE_AGENT);
}
__device__ __forceinline__ void gstore2(float* p, float x, float y){
  union { u64 u_; float f[2]; } v; v.f[0]=x; v.f[1]=y;
  __hip_atomic_store((u64*)p, v.u_, __ATOMIC_RELAXED, __HIP_MEMORY_SCOPE_AGENT);
}

// packed fp32 FMA: d = a*b + d (2 lanes) — gfx950's full-rate fp32 path.
__device__ __forceinline__ void pkfma(float2& d, float2 a, float2 b){
  asm("v_pk_fma_f32 %0, %1, %2, %0" : "+v"(d) : "v"(a), "v"(b));
}

// Fence-free two-level grid barrier (see R1/R2 notes).
__device__ __forceinline__ void gbar(unsigned* base, unsigned bi, int w) {
  asm volatile("s_waitcnt vmcnt(0)" ::: "memory");
  __syncthreads();
  if (threadIdx.x == 0) {
    unsigned* xcd  = base + 16 + 16*(w & 7);   // byte 64 + 64*(w&7)
    unsigned* glob = base;                      // byte 0
    unsigned* rel  = base + 144;                // byte 576
    __hip_atomic_fetch_add(xcd, 1u, __ATOMIC_RELAXED, __HIP_MEMORY_SCOPE_AGENT);
    if (w < 8) {
      unsigned* mine = base + 16 + 16*w;
      while (__hip_atomic_load(mine, __ATOMIC_RELAXED, __HIP_MEMORY_SCOPE_AGENT) < bi*32u)
        __builtin_amdgcn_s_sleep(1);
      __hip_atomic_fetch_add(glob, 1u, __ATOMIC_RELAXED, __HIP_MEMORY_SCOPE_AGENT);
    }
    if (w == 0) {
      while (__hip_atomic_load(glob, __ATOMIC_RELAXED, __HIP_MEMORY_SCOPE_AGENT) < bi*8u)
        __builtin_amdgcn_s_sleep(1);
      __hip_atomic_store(rel, bi, __ATOMIC_RELAXED, __HIP_MEMORY_SCOPE_AGENT);
    } else {
      while (__hip_atomic_load(rel, __ATOMIC_RELAXED, __HIP_MEMORY_SCOPE_AGENT) < bi)
        __builtin_amdgcn_s_sleep(2);
    }
  }
  __syncthreads();
}

// ---------------- persistent kernel (grid == #CUs, 512 thr = 8 waves/CU) ------

__global__ __launch_bounds__(NTHR, 2)
void lstm_main(Params P) {
  extern __shared__ float smem[];

  const bool bfout = (*P.flag) != 0;

  const int w   = blockIdx.x;
  const int tid = threadIdx.x;
  // phase A: WG owns 40 unique columns, all 64 rows.
  // 8 cgr x 16 rgr x 4 ksl; each thread: 4 rows (rgr+16i) x 5 cols x 128 k.
  const int c0  = w * 40;
  const int cgr = tid & 7;          // 8 col groups x 5 cols
  const int rgr = (tid >> 3) & 15;  // rows rgr + 16*i, i=0..3
  const int ksl = tid >> 7;         // k-quarter 0..3 (128 k each)
  const int cl  = cgr * 5;
  // phase B mapping: batch pb, quarter ph0; 64 hg x 2 hp, 8-way k-split
  const int pb  = w >> 2;
  const int ph0 = (w & 3) * 128;
  const int hg  = tid & 63;         // hp pair base = ph0 + 2*hg (wave-coalesced)
  const int kq8 = tid >> 6;         // k-eighth 0..7 (wave-uniform -> LB broadcast)

  // ---- one-time init: U strip + per-column input-proj weights into LDS ----
  for (int e = tid; e < 40*512; e += NTHR) {
    int c = e >> 9, k = e & 511;
    int cg = c0 + c, g = cg >> 9, cc = cg & 511;
    US(c, k) = P.Ucat[((size_t)g*HID + k)*HID + cc];
  }
  for (int e = tid; e < 40*36; e += NTHR) {
    int c = e / 36, jj = e % 36;
    int cg = c0 + c, g = cg >> 9, cc = cg & 511;
    float v = 0.f;
    if (jj == 32) {            // bias slot
      v = g < 4  ? P.Bm[g*HID + cc]
        : g < 12 ? P.Bx[(g-4)*HID + cc]
                 : P.Bx[(8 + g-12)*HID + cc];
    } else if (jj < 32 && g < 4) {
      v = P.Wm[((size_t)g*32 + jj)*HID + cc];
    } else if (jj < 3) {
      int p = (g < 12) ? (g-4) : (8 + g-12);
      v = P.Wx[((size_t)p*3 + jj)*HID + cc];
    }
    WML(c, jj) = v;
  }
  __syncthreads();

  unsigned bi = 0;

  // prefetch registers for Hg staging (8 x 8B per thread = 4 planes x 32 k)
  u64 pre[8];
  auto hgld = [&](int kcc) {
#pragma unroll
    for (int u = 0; u < 8; ++u) {
      int e2 = tid + u*NTHR;
      int k  = (e2 & 15) * 2;         // 0..30
      int b  = (e2 >> 4) & 63;
      int q  = e2 >> 10;              // 0..3
      pre[u] = gload2(&P.Hg[(size_t)b*HID + q*128 + kcc + k]);
    }
  };

  for (int t = 0; t < NSTEP; ++t) {
    // ===== phase A: z[64][40] = h @ Us (+input proj) -> Gall =====
    for (int e = tid; e < 64*32; e += NTHR) {
      int b = e >> 5, j = e & 31;
      YA(b, j) = P.Yt[((size_t)t*BATCH + b)*32 + j];
    }
    for (int e = tid; e < 8*64*3; e += NTHR) {
      int j2 = e % 3; int r = e / 3; int b = r & 63; int a = r >> 6;
      XA(a, b, j2) = P.Xt[(((size_t)t*8 + a)*BATCH + b)*3 + j2];
    }

    hgld(0);   // issue chunk-0 loads; land under LDS writes

    float2 acc2[4][5];
#pragma unroll
    for (int i=0;i<4;++i)
#pragma unroll
      for (int j=0;j<5;++j) { acc2[i][j].x=0.f; acc2[i][j].y=0.f; }

    for (int kc = 0; kc < 128; kc += 32) {   // 4 chunks of 32 k per quarter
      __syncthreads();                       // prev chunk's HA reads done
#pragma unroll
      for (int u = 0; u < 8; ++u) {          // regs -> LDS
        int e2 = tid + u*NTHR;
        int k  = (e2 & 15) * 2;
        int b  = (e2 >> 4) & 63;
        int q  = e2 >> 10;
        union { u64 u_; float f[2]; } v; v.u_ = pre[u];
        float2 t2; t2.x = v.f[0]; t2.y = v.f[1];
        *(float2*)&HA(q, b, k) = t2;
      }
      __syncthreads();
      if (kc + 32 < 128) hgld(kc + 32);      // next chunk in flight over compute

      const int kbase = ksl*128 + kc;
#pragma unroll 2
      for (int kk = 0; kk < 32; kk += 4) {
        float4 h0 = *(const float4*)&HA(ksl, rgr,      kk);
        float4 h1 = *(const float4*)&HA(ksl, rgr+16,   kk);
        float4 h2 = *(const float4*)&HA(ksl, rgr+32,   kk);
        float4 h3 = *(const float4*)&HA(ksl, rgr+48,   kk);
#pragma unroll
        for (int j = 0; j < 5; ++j) {
          float4 uv = *(const float4*)&US(cl+j, kbase+kk);
          float2 ulo; ulo.x = uv.x; ulo.y = uv.y;
          float2 uhi; uhi.x = uv.z; uhi.y = uv.w;
          float2 a0; a0.x = h0.x; a0.y = h0.y;  pkfma(acc2[0][j], a0, ulo);
          float2 b0; b0.x = h0.z; b0.y = h0.w;  pkfma(acc2[0][j], b0, uhi);
          float2 a1; a1.x = h1.x; a1.y = h1.y;  pkfma(acc2[1][j], a1, ulo);
          float2 b1; b1.x = h1.z; b1.y = h1.w;  pkfma(acc2[1][j], b1, uhi);
          float2 a2; a2.x = h2.x; a2.y = h2.y;  pkfma(acc2[2][j], a2, ulo);
          float2 b2; b2.x = h2.z; b2.y = h2.w;  pkfma(acc2[2][j], b2, uhi);
          float2 a3; a3.x = h3.x; a3.y = h3.y;  pkfma(acc2[3][j], a3, ulo);
          float2 b3; b3.x = h3.z; b3.y = h3.w;  pkfma(acc2[3][j], b3, uhi);
        }
      }
    }

    // fold packed halves
    float accs[4][5];
#pragma unroll
    for (int i=0;i<4;++i)
#pragma unroll
      for (int j=0;j<5;++j) accs[i][j] = acc2[i][j].x + acc2[i][j].y;

    // ---- 4-way k reduction via dead HA zone (stride 22, float2) ----
    __syncthreads();                          // all HA reads done before overlay
    if (ksl) {                                // tid 128..511
      float* r = &smem[L_REDA + (tid-128)*22];
#pragma unroll
      for (int p=0;p<10;++p) {
        float2 t2; t2.x = accs[(2*p)/5][(2*p)%5]; t2.y = accs[(2*p+1)/5][(2*p+1)%5];
        *(float2*)&r[2*p] = t2;
      }
    }
    __syncthreads();
    if (!ksl) {                               // tid 0..127: add 3 partials
#pragma unroll
      for (int q2 = 0; q2 < 3; ++q2) {
        const float* r = &smem[L_REDA + (tid + q2*128)*22];
#pragma unroll
        for (int p=0;p<10;++p) {
          float2 t2 = *(const float2*)&r[2*p];
          accs[(2*p)/5][(2*p)%5]   += t2.x;
          accs[(2*p+1)/5][(2*p+1)%5] += t2.y;
        }
      }

      // ---- epilogue: input projection + bias + nonlinearity -> GB ----
      const int col0 = c0 + cl;
      const int gA = col0 >> 9, gB2 = (col0 + 4) >> 9;
      if (gA == gB2 && gA < 4) {
        // uniform main-gate fast path: float4 blocks over Y[32]
#pragma unroll
        for (int jb = 0; jb < 8; ++jb) {
          float4 wm0 = *(const float4*)&WML(cl+0, 4*jb);
          float4 wm1 = *(const float4*)&WML(cl+1, 4*jb);
          float4 wm2 = *(const float4*)&WML(cl+2, 4*jb);
          float4 wm3 = *(const float4*)&WML(cl+3, 4*jb);
          float4 wm4 = *(const float4*)&WML(cl+4, 4*jb);
#pragma unroll
          for (int i=0;i<4;++i) {
            float4 ya = *(const float4*)&YA(rgr+16*i, 4*jb);
            accs[i][0] += ya.x*wm0.x + ya.y*wm0.y + ya.z*wm0.z + ya.w*wm0.w;
            accs[i][1] += ya.x*wm1.x + ya.y*wm1.y + ya.z*wm1.z + ya.w*wm1.w;
            accs[i][2] += ya.x*wm2.x + ya.y*wm2.y + ya.z*wm2.z + ya.w*wm2.w;
            accs[i][3] += ya.x*wm3.x + ya.y*wm3.y + ya.z*wm3.z + ya.w*wm3.w;
            accs[i][4] += ya.x*wm4.x + ya.y*wm4.y + ya.z*wm4.z + ya.w*wm4.w;
          }
        }
#pragma unroll
        for (int i=0;i<4;++i)
#pragma unroll
          for (int j=0;j<5;++j) {
            float v = accs[i][j] + WML(cl+j, 32);
            v = (gA == 2) ? tanhf(v) : sigf(v);
            GB(rgr + 16*i, cl+j) = v;
          }
      } else {
        // per-column path (x-gates and gate-straddling groups)
        for (int j = 0; j < 5; ++j) {
          int c = cl + j, cg = c0 + c, g = cg >> 9;
          if (g < 4) {
#pragma unroll
            for (int i=0;i<4;++i) {
              int row = rgr + 16*i;
              float s = WML(c, 32);
#pragma unroll
              for (int jb = 0; jb < 8; ++jb) {
                float4 ya = *(const float4*)&YA(row, 4*jb);
                float4 wm = *(const float4*)&WML(c, 4*jb);
                s += ya.x*wm.x + ya.y*wm.y + ya.z*wm.z + ya.w*wm.w;
              }
              float v = accs[i][j] + s;
              GB(row, c) = (g == 2) ? tanhf(v) : sigf(v);
            }
          } else if (g < 12) {
            int p = g-4; int a = (p==0) ? 0 : 1;  // ref quirk: i_x 2..8 all read x2
#pragma unroll
            for (int i=0;i<4;++i) {
              int row = rgr + 16*i;
              float s = WML(c, 32);
              for (int jj = 0; jj < 3; ++jj)
                s += XA(a, row, jj) * WML(c, jj);
              GB(row, c) = sigf(accs[i][j] + s);
            }
          } else {
            int p = g-12;
#pragma unroll
            for (int i=0;i<4;++i) {
              int row = rgr + 16*i;
              float s = WML(c, 32);
              for (int jj = 0; jj < 3; ++jj)
                s += XA(p, row, jj) * WML(c, jj);
              GB(row, c) = tanhf(accs[i][j] + s);
            }
          }
        }
      }
    }
    __syncthreads();
    // cooperative coalesced Gall store: float2, pair never straddles a gate
    for (int e = tid; e < 64*20; e += NTHR) {
      int row = e / 20, p = e % 20;
      int cc2 = c0 + 2*p;
      int g = cc2 >> 9, cc = cc2 & 511;
      gstore2(&P.Gall[((size_t)g*BATCH + row)*HID + cc], GB(row, 2*p), GB(row, 2*p+1));
    }

    gbar(P.bar, ++bi, w);

    // ===== phase B: m = l_all @ W_a, softmax mix, state update =====
    for (int e = tid; e < 9*256; e += NTHR) {   // 8B-wide Gall staging
      int j = e >> 8, h2 = (e & 255) << 1;
      union { u64 u_; float f[2]; } a, b2;
      if (j == 0) {
        a.u_  = gload2(&P.Gall[((size_t)0*BATCH+pb)*HID+h2]);
        b2.u_ = gload2(&P.Gall[((size_t)2*BATCH+pb)*HID+h2]);
      } else {
        int p = j-1;
        a.u_  = gload2(&P.Gall[((size_t)(4+p)*BATCH+pb)*HID+h2]);
        b2.u_ = gload2(&P.Gall[((size_t)(12+p)*BATCH+pb)*HID+h2]);
      }
      float2 t2; t2.x = a.f[0]*b2.f[0]; t2.y = a.f[1]*b2.f[1];
      *(float2*)&LB(j, h2) = t2;
    }
    __syncthreads();

    // each thread: 2 hp cols x 9 j over 64 k; LB reads are wave-broadcast
    // (kq8 wave-uniform), Wa float2 reads wave-coalesced (512B/instr).
    float ab[2][9];
#pragma unroll
    for (int s=0;s<2;++s)
#pragma unroll
      for (int j=0;j<9;++j) ab[s][j]=0.f;
    {
      const int k0 = kq8 * 64;
      const float* wa = P.Wa + (size_t)k0*HID + ph0 + hg*2;
#pragma unroll 4
      for (int k = 0; k < 64; k += 4) {
        float2 w0 = *(const float2*)&wa[(size_t)(k+0)*HID];
        float2 w1 = *(const float2*)&wa[(size_t)(k+1)*HID];
        float2 w2 = *(const float2*)&wa[(size_t)(k+2)*HID];
        float2 w3 = *(const float2*)&wa[(size_t)(k+3)*HID];
#pragma unroll
        for (int j=0;j<9;++j) {
          float4 l4 = *(const float4*)&LB(j, k0+k);
          ab[0][j] += l4.x*w0.x; ab[0][j] += l4.y*w1.x;
          ab[0][j] += l4.z*w2.x; ab[0][j] += l4.w*w3.x;
          ab[1][j] += l4.x*w0.y; ab[1][j] += l4.y*w1.y;
          ab[1][j] += l4.z*w2.y; ab[1][j] += l4.w*w3.y;
        }
      }
    }
    // 8-way k reduction, ping-pong in dead HA zone, stride 19 (conflict-free)
    if (tid >= 256) {                    // hop1 write: kq8 4..7
      float* r = &smem[L_RA + (tid-256)*19];
#pragma unroll
      for (int s=0;s<2;++s)
#pragma unroll
        for (int j=0;j<9;++j) r[s*9+j] = ab[s][j];
    }
    __syncthreads();
    if (tid < 256) {                     // hop1 add; hop2 write: kq8 2..3
      const float* r = &smem[L_RA + tid*19];
#pragma unroll
      for (int s=0;s<2;++s)
#pragma unroll
        for (int j=0;j<9;++j) ab[s][j] += r[s*9+j];
      if (tid >= 128) {
        float* r2 = &smem[L_RB + (tid-128)*19];
#pragma unroll
        for (int s=0;s<2;++s)
#pragma unroll
          for (int j=0;j<9;++j) r2[s*9+j] = ab[s][j];
      }
    }
    __syncthreads();
    if (tid < 128) {                     // hop2 add; hop3 write: kq8 1 (reuse RA)
      const float* r = &smem[L_RB + tid*19];
#pragma unroll
      for (int s=0;s<2;++s)
#pragma unroll
        for (int j=0;j<9;++j) ab[s][j] += r[s*9+j];
      if (tid >= 64) {
        float* r2 = &smem[L_RA + (tid-64)*19];
#pragma unroll
        for (int s=0;s<2;++s)
#pragma unroll
          for (int j=0;j<9;++j) r2[s*9+j] = ab[s][j];
      }
    }
    __syncthreads();
    if (tid < 64) {                      // hop3 add; publish m pairs
      const float* r = &smem[L_RA + tid*19];
      float* mp = &smem[L_MPZ + tid*19];
#pragma unroll
      for (int s=0;s<2;++s)
#pragma unroll
        for (int j=0;j<9;++j) mp[s*9+j] = ab[s][j] + r[s*9+j];
    }
    __syncthreads();
    if (tid < 128) {
      const int hp = ph0 + tid;
      const float* mf = &smem[L_MPZ + (tid>>1)*19 + (tid&1)*9];
      float co = P.Cg[(size_t)pb*HID + hp];
      float ba = P.Ba[hp];
      float u9[9], mx = -1e30f;
#pragma unroll
      for (int j=0;j<9;++j) {
        u9[j] = tanhf(mf[j]*co + ba);
        mx = fmaxf(mx, u9[j]);
      }
      float ssum = 0.f, L = 0.f;
#pragma unroll
      for (int j=0;j<9;++j) {
        float e2 = expf(u9[j]-mx);
        ssum += e2;
        L += e2 * LB(j, hp);
      }
      L /= ssum;
      float f = gload(&P.Gall[((size_t)1*BATCH+pb)*HID + hp]);
      float o = gload(&P.Gall[((size_t)3*BATCH+pb)*HID + hp]);
      float cn = f*co + L;
      float hn = o*tanhf(cn);
      P.Cg[(size_t)pb*HID + hp] = cn;
      gstore(&P.Hg[(size_t)pb*HID + hp], hn);
      size_t iseq = (size_t)BATCH*HID + ((size_t)pb*NSTEP + t)*HID + hp;
      if (bfout) ((bf16*)P.out)[iseq] = __float2bfloat16(hn);
      else       ((float*)P.out)[iseq] = hn;
      if (t == NSTEP-1) {
        size_t ih = (size_t)pb*HID + hp;
        if (bfout) ((bf16*)P.out)[ih] = __float2bfloat16(hn);
        else       ((float*)P.out)[ih] = hn;
      }
    }

    gbar(P.bar, ++bi, w);
  }
}

// ---------------- host entry --------------------------------------------------

extern "C" void kernel_launch(void* const* d_in, const int* in_sizes, int n_in,
                              void* d_out, int out_size, void* d_ws, size_t ws_size,
                              hipStream_t stream) {
  char* ws = (char*)d_ws;

  RawIn R;
  R.Y = d_in[0];
  for (int i = 0; i < 8; ++i) R.x[i] = d_in[1+i];
  R.W_i=d_in[9];  R.U_i=d_in[10]; R.b_i=d_in[11];
  R.W_f=d_in[12]; R.U_f=d_in[13]; R.b_f=d_in[14];
  R.W_c=d_in[15]; R.U_c=d_in[16]; R.b_c=d_in[17];
  R.W_o=d_in[18]; R.U_o=d_in[19]; R.b_o=d_in[20];
  R.W_ix=d_in[21]; R.U_ix=d_in[22]; R.b_ix=d_in[23];
  R.W_cx=d_in[24]; R.U_cx=d_in[25]; R.b_cx=d_in[26];
  R.W_a =d_in[27]; R.b_a =d_in[28];
  R.Ucat=(float*)(ws+OFF_UCAT); R.Wa=(float*)(ws+OFF_WA);
  R.Wm=(float*)(ws+OFF_WM); R.Wx=(float*)(ws+OFF_WX);
  R.Bm=(float*)(ws+OFF_BM); R.Bx=(float*)(ws+OFF_BX); R.Ba=(float*)(ws+OFF_BA);
  R.Yt=(float*)(ws+OFF_YT); R.Xt=(float*)(ws+OFF_XT);
  R.flag=(const unsigned*)(ws+OFF_FLAG);

  Params P;
  P.Ucat=R.Ucat; P.Wa=R.Wa; P.Wm=R.Wm; P.Wx=R.Wx;
  P.Bm=R.Bm; P.Bx=R.Bx; P.Ba=R.Ba; P.Yt=R.Yt; P.Xt=R.Xt;
  P.Hg=(float*)(ws+OFF_HG); P.Cg=(float*)(ws+OFF_CG); P.Gall=(float*)(ws+OFF_GALL);
  P.bar=(unsigned*)(ws+OFF_BAR);
  P.flag=R.flag;
  P.out=d_out;

  // zero barrier block + flag + Hg + Cg (ws is poisoned 0xAA before every call)
  hipMemsetAsync(d_ws, 0, OFF_GALL, stream);

  k_detect<<<1, 64, 0, stream>>>((const unsigned short*)d_in[10], (unsigned*)(ws+OFF_FLAG));
  k_conv_w <<<21899, 256, 0, stream>>>(R);
  k_conv_in<<<14336, 256, 0, stream>>>(R);

  const int smemBytes = L_TOT * 4;   // 152064 B < 160 KB/CU -> 1 WG/CU, 8 waves
  hipFuncSetAttribute((const void*)lstm_main,
                      hipFuncAttributeMaxDynamicSharedMemorySize, smemBytes);
  lstm_main<<<dim3(GRID), dim3(NTHR), smemBytes, stream>>>(P);
}

// Round 6
// 114741.724 us; speedup vs baseline: 1.0890x; 1.0890x over previous
//
#include <hip/hip_runtime.h>
#include <hip/hip_bf16.h>

typedef __hip_bfloat16 bf16;
typedef unsigned long long u64;

#define NSTEP 1024
#define BATCH 64
#define HID   512
#define GRID  256
#define NTHR  512

// ---- workspace layout (bytes) ----
// barrier block [0,1024): global@0, xcd[x]@64+64x (x=0..7), rel@576, flag@640
#define OFF_BAR   0u
#define OFF_FLAG  640u
#define OFF_HG    1024u
#define OFF_CG    132096u
#define OFF_GALL  263168u
#define OFF_UCAT  2884608u
#define OFF_WA    23856128u
#define OFF_WM    24904704u
#define OFF_WX    25166848u
#define OFF_BM    25265152u
#define OFF_BX    25273344u
#define OFF_BA    25306112u
#define OFF_YT    25308160u
#define OFF_XT    33696768u

// ---- LDS carve (float indices) ----
// persistent: US[40][524], WML[40][36], HA[4][64][36]
// overlay A : YA[64][36], XA[8][64][3], GB[64][40]; REDA in dead HA zone
// overlay B : LB[9][520] over YA/XA/GB head; RA/RB/MPZ in dead HA zone
#define L_US    0         /* 40*524 = 20960 */
#define L_WML   20960     /* 40*36 = 1440 -> 22400 */
#define L_HA    22400     /* 4*2304 = 9216 -> 31616 */
#define L_YA    31616     /* 64*36 = 2304 -> 33920 */
#define L_XA    33920     /* 1536 -> 35456 */
#define L_GB    35456     /* 2560 -> 38016 */
#define L_REDA  22400     /* phase A red: 384*22 = 8448 (HA dead) */
#define L_LB    31616     /* phase B: 9*520 = 4680 -> 36296 (YA/XA/GB dead) */
#define L_RA    22400     /* phase B hop A: 256*19 = 4864 */
#define L_RB    27264     /* phase B hop B: 128*19 = 2432 -> 29696 */
#define L_MPZ   29696     /* phase B final m: 64*19 = 1216 -> 30912 */
#define L_TOT   38016     /* 152064 B < 160 KB */

#define US(c,k)    smem[L_US  + (c)*524 + (k)]
#define WML(c,j)   smem[L_WML + (c)*36  + (j)]
#define HA(q,b,k)  smem[L_HA  + (q)*2304 + (b)*36 + (k)]
#define YA(b,j)    smem[L_YA  + (b)*36 + (j)]
#define XA(a,b,j)  smem[L_XA  + ((a)*64 + (b))*3 + (j)]
#define GB(r,c)    smem[L_GB  + (r)*40 + (c)]
#define LB(j,h)    smem[L_LB  + (j)*520 + (h)]

struct RawIn {
  const void *Y, *x[8];
  const void *W_i,*U_i,*b_i, *W_f,*U_f,*b_f, *W_c,*U_c,*b_c, *W_o,*U_o,*b_o;
  const void *W_ix,*U_ix,*b_ix, *W_cx,*U_cx,*b_cx, *W_a,*b_a;
  float *Ucat,*Wa,*Wm,*Wx,*Bm,*Bx,*Ba,*Yt,*Xt;
  const unsigned *flag;
};

struct Params {
  const float *Ucat,*Wa,*Wm,*Wx,*Bm,*Bx,*Ba,*Yt,*Xt;
  float *Hg,*Cg,*Gall;
  unsigned *bar;
  const unsigned *flag;
  void *out;
};

// ---------------- dtype probe -------------------------------------------------
__global__ void k_detect(const unsigned short* __restrict__ p, unsigned* flag) {
  if (blockIdx.x == 0 && threadIdx.x == 0) {
    int cnt = 0;
    for (int i = 0; i < 64; ++i) {
      unsigned e = (p[i] >> 7) & 0xFF;
      cnt += (e >= 0x60 && e <= 0x7C) || (p[i] & 0x7FFF) == 0;
    }
    *flag = (cnt >= 56) ? 1u : 0u;   // 1 = bf16, 0 = fp32
  }
}

__device__ __forceinline__ float cvt(const void* p, size_t i, bool bf) {
  return bf ? (float)((const bf16*)p)[i] : ((const float*)p)[i];
}

// ---------------- weight normalization ---------------------------------------
#define NWTOT 5605888
__global__ __launch_bounds__(256)
void k_conv_w(RawIn R) {
  const bool bf = (*R.flag) != 0;
  for (size_t i = blockIdx.x*256 + threadIdx.x; i < NWTOT; i += (size_t)gridDim.x*256) {
    if (i < 5242880) {           // Ucat [20][512][512]
      size_t g = i >> 18, r = i & 262143;
      const void* s = g<4 ? (g==0?R.U_i:g==1?R.U_f:g==2?R.U_c:R.U_o)
                    : g<12 ? R.U_ix : R.U_cx;
      size_t off = g<4 ? r : g<12 ? (g-4)*262144 + r : (g-12)*262144 + r;
      R.Ucat[i] = cvt(s, off, bf);
    } else {
      size_t j = i - 5242880;
      if (j < 262144) { R.Wa[j] = cvt(R.W_a, j, bf); }
      else {
        size_t j2 = j - 262144;
        if (j2 < 65536) {        // Wm [4][32][512]
          size_t g = j2 >> 14, r = j2 & 16383;
          const void* s = g==0?R.W_i:g==1?R.W_f:g==2?R.W_c:R.W_o;
          R.Wm[j2] = cvt(s, r, bf);
        } else {
          size_t j3 = j2 - 65536;
          if (j3 < 24576) {      // Wx [16][3][512]
            size_t p = j3 / 1536, r = j3 % 1536;
            R.Wx[j3] = p < 8 ? cvt(R.W_ix, p*1536 + r, bf)
                             : cvt(R.W_cx, (p-8)*1536 + r, bf);
          } else {
            size_t j4 = j3 - 24576;
            if (j4 < 2048) {     // Bm [4][512]
              size_t g = j4 >> 9, c = j4 & 511;
              const void* s = g==0?R.b_i:g==1?R.b_f:g==2?R.b_c:R.b_o;
              R.Bm[j4] = cvt(s, c, bf);
            } else {
              size_t j5 = j4 - 2048;
              if (j5 < 8192) {   // Bx [16][512]
                size_t p = j5 >> 9, c = j5 & 511;
                R.Bx[j5] = p < 8 ? cvt(R.b_ix, p*512 + c, bf)
                                 : cvt(R.b_cx, (p-8)*512 + c, bf);
              } else {
                size_t j6 = j5 - 8192;       // Ba [512]
                R.Ba[j6] = cvt(R.b_a, j6, bf);
              }
            }
          }
        }
      }
    }
  }
}

// ---------------- input normalization (time-major pack) -----------------------
#define NYT 2097152
#define NXT 1572864
__global__ __launch_bounds__(256)
void k_conv_in(RawIn R) {
  const bool bf = (*R.flag) != 0;
  for (size_t i = blockIdx.x*256 + threadIdx.x; i < NYT+NXT; i += (size_t)gridDim.x*256) {
    if (i < NYT) {               // Yt [t][b][32]
      size_t j = i & 31, b = (i >> 5) & 63, t = i >> 11;
      R.Yt[i] = cvt(R.Y, (b*32 + j)*NSTEP + t, bf);
    } else {                     // Xt [t][8][b][3]
      size_t i2 = i - NYT;
      size_t j = i2 % 3, r = i2 / 3;
      size_t b = r & 63; r >>= 6;
      size_t a = r & 7, t = r >> 3;
      R.Xt[i2] = cvt(R.x[a], (b*3 + j)*NSTEP + t, bf);
    }
  }
}

// ---------------- helpers -----------------------------------------------------

__device__ __forceinline__ float sigf(float v){ return 1.f/(1.f+expf(-v)); }

__device__ __forceinline__ float gload(const float* p){
  return __hip_atomic_load(p, __ATOMIC_RELAXED, __HIP_MEMORY_SCOPE_AGENT);
}
__device__ __forceinline__ u64 gload2(const float* p){
  return __hip_atomic_load((const u64*)p, __ATOMIC_RELAXED, __HIP_MEMORY_SCOPE_AGENT);
}
__device__ __forceinline__ void gstore(float* p, float v){
  __hip_atomic_store(p, v, __ATOMIC_RELAXED, __HIP_MEMORY_SCOPE_AGENT);
}
__device__ __forceinline__ void gstore2(float* p, float x, float y){
  union { u64 u_; float f[2]; } v; v.f[0]=x; v.f[1]=y;
  __hip_atomic_store((u64*)p, v.u_, __ATOMIC_RELAXED, __HIP_MEMORY_SCOPE_AGENT);
}

// Fence-free two-level grid barrier (see R1/R2 notes).
__device__ __forceinline__ void gbar(unsigned* base, unsigned bi, int w) {
  asm volatile("s_waitcnt vmcnt(0)" ::: "memory");
  __syncthreads();
  if (threadIdx.x == 0) {
    unsigned* xcd  = base + 16 + 16*(w & 7);   // byte 64 + 64*(w&7)
    unsigned* glob = base;                      // byte 0
    unsigned* rel  = base + 144;                // byte 576
    __hip_atomic_fetch_add(xcd, 1u, __ATOMIC_RELAXED, __HIP_MEMORY_SCOPE_AGENT);
    if (w < 8) {
      unsigned* mine = base + 16 + 16*w;
      while (__hip_atomic_load(mine, __ATOMIC_RELAXED, __HIP_MEMORY_SCOPE_AGENT) < bi*32u)
        __builtin_amdgcn_s_sleep(1);
      __hip_atomic_fetch_add(glob, 1u, __ATOMIC_RELAXED, __HIP_MEMORY_SCOPE_AGENT);
    }
    if (w == 0) {
      while (__hip_atomic_load(glob, __ATOMIC_RELAXED, __HIP_MEMORY_SCOPE_AGENT) < bi*8u)
        __builtin_amdgcn_s_sleep(1);
      __hip_atomic_store(rel, bi, __ATOMIC_RELAXED, __HIP_MEMORY_SCOPE_AGENT);
    } else {
      while (__hip_atomic_load(rel, __ATOMIC_RELAXED, __HIP_MEMORY_SCOPE_AGENT) < bi)
        __builtin_amdgcn_s_sleep(2);
    }
  }
  __syncthreads();
}

// ---------------- persistent kernel (grid == #CUs, 512 thr = 8 waves/CU) ------

__global__ __launch_bounds__(NTHR, 2)
void lstm_main(Params P) {
  extern __shared__ float smem[];

  const bool bfout = (*P.flag) != 0;

  const int w   = blockIdx.x;
  const int tid = threadIdx.x;
  // phase A: WG owns 40 unique columns, all 64 rows.
  // 8 cgr x 16 rgr x 4 ksl; each thread: 4 rows (rgr+16i) x 5 cols x 128 k.
  const int c0  = w * 40;
  const int cgr = tid & 7;          // 8 col groups x 5 cols
  const int rgr = (tid >> 3) & 15;  // rows rgr + 16*i, i=0..3
  const int ksl = tid >> 7;         // k-quarter 0..3 (128 k each)
  const int cl  = cgr * 5;
  // phase B mapping: batch pb, quarter ph0; 64 hg x 2 hp, 8-way k-split
  const int pb  = w >> 2;
  const int ph0 = (w & 3) * 128;
  const int hg  = tid & 63;         // hp pair base = ph0 + 2*hg (wave-coalesced)
  const int kq8 = tid >> 6;         // k-eighth 0..7 (wave-uniform -> LB broadcast)

  // ---- one-time init: U strip + per-column input-proj weights into LDS ----
  for (int e = tid; e < 40*512; e += NTHR) {
    int c = e >> 9, k = e & 511;
    int cg = c0 + c, g = cg >> 9, cc = cg & 511;
    US(c, k) = P.Ucat[((size_t)g*HID + k)*HID + cc];
  }
  for (int e = tid; e < 40*36; e += NTHR) {
    int c = e / 36, jj = e % 36;
    int cg = c0 + c, g = cg >> 9, cc = cg & 511;
    float v = 0.f;
    if (jj == 32) {            // bias slot
      v = g < 4  ? P.Bm[g*HID + cc]
        : g < 12 ? P.Bx[(g-4)*HID + cc]
                 : P.Bx[(8 + g-12)*HID + cc];
    } else if (jj < 32 && g < 4) {
      v = P.Wm[((size_t)g*32 + jj)*HID + cc];
    } else if (jj < 3) {
      int p = (g < 12) ? (g-4) : (8 + g-12);
      v = P.Wx[((size_t)p*3 + jj)*HID + cc];
    }
    WML(c, jj) = v;
  }
  __syncthreads();

  unsigned bi = 0;

  // prefetch registers for Hg staging (8 x 8B per thread = 4 planes x 32 k)
  u64 pre[8];
  auto hgld = [&](int kcc) {
#pragma unroll
    for (int u = 0; u < 8; ++u) {
      int e2 = tid + u*NTHR;
      int k  = (e2 & 15) * 2;         // 0..30
      int b  = (e2 >> 4) & 63;
      int q  = e2 >> 10;              // 0..3
      pre[u] = gload2(&P.Hg[(size_t)b*HID + q*128 + kcc + k]);
    }
  };

  for (int t = 0; t < NSTEP; ++t) {
    // ===== phase A: z[64][40] = h @ Us (+input proj) -> Gall =====
    for (int e = tid; e < 64*32; e += NTHR) {
      int b = e >> 5, j = e & 31;
      YA(b, j) = P.Yt[((size_t)t*BATCH + b)*32 + j];
    }
    for (int e = tid; e < 8*64*3; e += NTHR) {
      int j2 = e % 3; int r = e / 3; int b = r & 63; int a = r >> 6;
      XA(a, b, j2) = P.Xt[(((size_t)t*8 + a)*BATCH + b)*3 + j2];
    }

    hgld(0);   // issue chunk-0 loads; land under LDS writes

    float accs[4][5];
#pragma unroll
    for (int i=0;i<4;++i)
#pragma unroll
      for (int j=0;j<5;++j) accs[i][j]=0.f;

    for (int kc = 0; kc < 128; kc += 32) {   // 4 chunks of 32 k per quarter
      __syncthreads();                       // prev chunk's HA reads done
#pragma unroll
      for (int u = 0; u < 8; ++u) {          // regs -> LDS
        int e2 = tid + u*NTHR;
        int k  = (e2 & 15) * 2;
        int b  = (e2 >> 4) & 63;
        int q  = e2 >> 10;
        union { u64 u_; float f[2]; } v; v.u_ = pre[u];
        float2 t2; t2.x = v.f[0]; t2.y = v.f[1];
        *(float2*)&HA(q, b, k) = t2;
      }
      __syncthreads();
      if (kc + 32 < 128) hgld(kc + 32);      // next chunk in flight over compute

      const int kbase = ksl*128 + kc;
#pragma unroll 2
      for (int kk = 0; kk < 32; kk += 4) {
        float4 h0 = *(const float4*)&HA(ksl, rgr,      kk);
        float4 h1 = *(const float4*)&HA(ksl, rgr+16,   kk);
        float4 h2 = *(const float4*)&HA(ksl, rgr+32,   kk);
        float4 h3 = *(const float4*)&HA(ksl, rgr+48,   kk);
#pragma unroll
        for (int j = 0; j < 5; ++j) {
          float4 uv = *(const float4*)&US(cl+j, kbase+kk);
          accs[0][j] += h0.x*uv.x; accs[0][j] += h0.y*uv.y;
          accs[0][j] += h0.z*uv.z; accs[0][j] += h0.w*uv.w;
          accs[1][j] += h1.x*uv.x; accs[1][j] += h1.y*uv.y;
          accs[1][j] += h1.z*uv.z; accs[1][j] += h1.w*uv.w;
          accs[2][j] += h2.x*uv.x; accs[2][j] += h2.y*uv.y;
          accs[2][j] += h2.z*uv.z; accs[2][j] += h2.w*uv.w;
          accs[3][j] += h3.x*uv.x; accs[3][j] += h3.y*uv.y;
          accs[3][j] += h3.z*uv.z; accs[3][j] += h3.w*uv.w;
        }
      }
    }

    // ---- 4-way k reduction via dead HA zone (stride 22, float2) ----
    __syncthreads();                          // all HA reads done before overlay
    if (ksl) {                                // tid 128..511
      float* r = &smem[L_REDA + (tid-128)*22];
#pragma unroll
      for (int p=0;p<10;++p) {
        float2 t2; t2.x = accs[(2*p)/5][(2*p)%5]; t2.y = accs[(2*p+1)/5][(2*p+1)%5];
        *(float2*)&r[2*p] = t2;
      }
    }
    __syncthreads();
    if (!ksl) {                               // tid 0..127: add 3 partials
#pragma unroll
      for (int q2 = 0; q2 < 3; ++q2) {
        const float* r = &smem[L_REDA + (tid + q2*128)*22];
#pragma unroll
        for (int p=0;p<10;++p) {
          float2 t2 = *(const float2*)&r[2*p];
          accs[(2*p)/5][(2*p)%5]   += t2.x;
          accs[(2*p+1)/5][(2*p+1)%5] += t2.y;
        }
      }

      // ---- epilogue: input projection + bias + nonlinearity -> GB ----
      const int col0 = c0 + cl;
      const int gA = col0 >> 9, gB2 = (col0 + 4) >> 9;
      if (gA == gB2 && gA < 4) {
        // uniform main-gate fast path: float4 blocks over Y[32]
#pragma unroll
        for (int jb = 0; jb < 8; ++jb) {
          float4 wm0 = *(const float4*)&WML(cl+0, 4*jb);
          float4 wm1 = *(const float4*)&WML(cl+1, 4*jb);
          float4 wm2 = *(const float4*)&WML(cl+2, 4*jb);
          float4 wm3 = *(const float4*)&WML(cl+3, 4*jb);
          float4 wm4 = *(const float4*)&WML(cl+4, 4*jb);
#pragma unroll
          for (int i=0;i<4;++i) {
            float4 ya = *(const float4*)&YA(rgr+16*i, 4*jb);
            accs[i][0] += ya.x*wm0.x + ya.y*wm0.y + ya.z*wm0.z + ya.w*wm0.w;
            accs[i][1] += ya.x*wm1.x + ya.y*wm1.y + ya.z*wm1.z + ya.w*wm1.w;
            accs[i][2] += ya.x*wm2.x + ya.y*wm2.y + ya.z*wm2.z + ya.w*wm2.w;
            accs[i][3] += ya.x*wm3.x + ya.y*wm3.y + ya.z*wm3.z + ya.w*wm3.w;
            accs[i][4] += ya.x*wm4.x + ya.y*wm4.y + ya.z*wm4.z + ya.w*wm4.w;
          }
        }
#pragma unroll
        for (int i=0;i<4;++i)
#pragma unroll
          for (int j=0;j<5;++j) {
            float v = accs[i][j] + WML(cl+j, 32);
            v = (gA == 2) ? tanhf(v) : sigf(v);
            GB(rgr + 16*i, cl+j) = v;
          }
      } else {
        // per-column path (x-gates and gate-straddling groups)
        for (int j = 0; j < 5; ++j) {
          int c = cl + j, cg = c0 + c, g = cg >> 9;
          if (g < 4) {
#pragma unroll
            for (int i=0;i<4;++i) {
              int row = rgr + 16*i;
              float s = WML(c, 32);
#pragma unroll
              for (int jb = 0; jb < 8; ++jb) {
                float4 ya = *(const float4*)&YA(row, 4*jb);
                float4 wm = *(const float4*)&WML(c, 4*jb);
                s += ya.x*wm.x + ya.y*wm.y + ya.z*wm.z + ya.w*wm.w;
              }
              float v = accs[i][j] + s;
              GB(row, c) = (g == 2) ? tanhf(v) : sigf(v);
            }
          } else if (g < 12) {
            int p = g-4; int a = (p==0) ? 0 : 1;  // ref quirk: i_x 2..8 all read x2
#pragma unroll
            for (int i=0;i<4;++i) {
              int row = rgr + 16*i;
              float s = WML(c, 32);
              for (int jj = 0; jj < 3; ++jj)
                s += XA(a, row, jj) * WML(c, jj);
              GB(row, c) = sigf(accs[i][j] + s);
            }
          } else {
            int p = g-12;
#pragma unroll
            for (int i=0;i<4;++i) {
              int row = rgr + 16*i;
              float s = WML(c, 32);
              for (int jj = 0; jj < 3; ++jj)
                s += XA(p, row, jj) * WML(c, jj);
              GB(row, c) = tanhf(accs[i][j] + s);
            }
          }
        }
      }
    }
    __syncthreads();
    // cooperative coalesced Gall store: float2, pair never straddles a gate
    for (int e = tid; e < 64*20; e += NTHR) {
      int row = e / 20, p = e % 20;
      int cc2 = c0 + 2*p;
      int g = cc2 >> 9, cc = cc2 & 511;
      gstore2(&P.Gall[((size_t)g*BATCH + row)*HID + cc], GB(row, 2*p), GB(row, 2*p+1));
    }

    gbar(P.bar, ++bi, w);

    // ===== phase B: m = l_all @ W_a, softmax mix, state update =====
    for (int e = tid; e < 9*256; e += NTHR) {   // 8B-wide Gall staging
      int j = e >> 8, h2 = (e & 255) << 1;
      union { u64 u_; float f[2]; } a, b2;
      if (j == 0) {
        a.u_  = gload2(&P.Gall[((size_t)0*BATCH+pb)*HID+h2]);
        b2.u_ = gload2(&P.Gall[((size_t)2*BATCH+pb)*HID+h2]);
      } else {
        int p = j-1;
        a.u_  = gload2(&P.Gall[((size_t)(4+p)*BATCH+pb)*HID+h2]);
        b2.u_ = gload2(&P.Gall[((size_t)(12+p)*BATCH+pb)*HID+h2]);
      }
      float2 t2; t2.x = a.f[0]*b2.f[0]; t2.y = a.f[1]*b2.f[1];
      *(float2*)&LB(j, h2) = t2;
    }
    __syncthreads();

    // each thread: 2 hp cols x 9 j over 64 k; LB reads are wave-broadcast
    // (kq8 wave-uniform), Wa float2 reads wave-coalesced (512B/instr).
    float ab[2][9];
#pragma unroll
    for (int s=0;s<2;++s)
#pragma unroll
      for (int j=0;j<9;++j) ab[s][j]=0.f;
    {
      const int k0 = kq8 * 64;
      const float* wa = P.Wa + (size_t)k0*HID + ph0 + hg*2;
#pragma unroll 4
      for (int k = 0; k < 64; k += 4) {
        float2 w0 = *(const float2*)&wa[(size_t)(k+0)*HID];
        float2 w1 = *(const float2*)&wa[(size_t)(k+1)*HID];
        float2 w2 = *(const float2*)&wa[(size_t)(k+2)*HID];
        float2 w3 = *(const float2*)&wa[(size_t)(k+3)*HID];
#pragma unroll
        for (int j=0;j<9;++j) {
          float4 l4 = *(const float4*)&LB(j, k0+k);
          ab[0][j] += l4.x*w0.x; ab[0][j] += l4.y*w1.x;
          ab[0][j] += l4.z*w2.x; ab[0][j] += l4.w*w3.x;
          ab[1][j] += l4.x*w0.y; ab[1][j] += l4.y*w1.y;
          ab[1][j] += l4.z*w2.y; ab[1][j] += l4.w*w3.y;
        }
      }
    }
    // 8-way k reduction, ping-pong in dead HA zone, stride 19 (conflict-free)
    if (tid >= 256) {                    // hop1 write: kq8 4..7
      float* r = &smem[L_RA + (tid-256)*19];
#pragma unroll
      for (int s=0;s<2;++s)
#pragma unroll
        for (int j=0;j<9;++j) r[s*9+j] = ab[s][j];
    }
    __syncthreads();
    if (tid < 256) {                     // hop1 add; hop2 write: kq8 2..3
      const float* r = &smem[L_RA + tid*19];
#pragma unroll
      for (int s=0;s<2;++s)
#pragma unroll
        for (int j=0;j<9;++j) ab[s][j] += r[s*9+j];
      if (tid >= 128) {
        float* r2 = &smem[L_RB + (tid-128)*19];
#pragma unroll
        for (int s=0;s<2;++s)
#pragma unroll
          for (int j=0;j<9;++j) r2[s*9+j] = ab[s][j];
      }
    }
    __syncthreads();
    if (tid < 128) {                     // hop2 add; hop3 write: kq8 1 (reuse RA)
      const float* r = &smem[L_RB + tid*19];
#pragma unroll
      for (int s=0;s<2;++s)
#pragma unroll
        for (int j=0;j<9;++j) ab[s][j] += r[s*9+j];
      if (tid >= 64) {
        float* r2 = &smem[L_RA + (tid-64)*19];
#pragma unroll
        for (int s=0;s<2;++s)
#pragma unroll
          for (int j=0;j<9;++j) r2[s*9+j] = ab[s][j];
      }
    }
    __syncthreads();
    if (tid < 64) {                      // hop3 add; publish m pairs
      const float* r = &smem[L_RA + tid*19];
      float* mp = &smem[L_MPZ + tid*19];
#pragma unroll
      for (int s=0;s<2;++s)
#pragma unroll
        for (int j=0;j<9;++j) mp[s*9+j] = ab[s][j] + r[s*9+j];
    }
    __syncthreads();
    if (tid < 128) {
      const int hp = ph0 + tid;
      const float* mf = &smem[L_MPZ + (tid>>1)*19 + (tid&1)*9];
      float co = P.Cg[(size_t)pb*HID + hp];
      float ba = P.Ba[hp];
      float u9[9], mx = -1e30f;
#pragma unroll
      for (int j=0;j<9;++j) {
        u9[j] = tanhf(mf[j]*co + ba);
        mx = fmaxf(mx, u9[j]);
      }
      float ssum = 0.f, L = 0.f;
#pragma unroll
      for (int j=0;j<9;++j) {
        float e2 = expf(u9[j]-mx);
        ssum += e2;
        L += e2 * LB(j, hp);
      }
      L /= ssum;
      float f = gload(&P.Gall[((size_t)1*BATCH+pb)*HID + hp]);
      float o = gload(&P.Gall[((size_t)3*BATCH+pb)*HID + hp]);
      float cn = f*co + L;
      float hn = o*tanhf(cn);
      P.Cg[(size_t)pb*HID + hp] = cn;
      gstore(&P.Hg[(size_t)pb*HID + hp], hn);
      size_t iseq = (size_t)BATCH*HID + ((size_t)pb*NSTEP + t)*HID + hp;
      if (bfout) ((bf16*)P.out)[iseq] = __float2bfloat16(hn);
      else       ((float*)P.out)[iseq] = hn;
      if (t == NSTEP-1) {
        size_t ih = (size_t)pb*HID + hp;
        if (bfout) ((bf16*)P.out)[ih] = __float2bfloat16(hn);
        else       ((float*)P.out)[ih] = hn;
      }
    }

    gbar(P.bar, ++bi, w);
  }
}

// ---------------- host entry --------------------------------------------------

extern "C" void kernel_launch(void* const* d_in, const int* in_sizes, int n_in,
                              void* d_out, int out_size, void* d_ws, size_t ws_size,
                              hipStream_t stream) {
  char* ws = (char*)d_ws;

  RawIn R;
  R.Y = d_in[0];
  for (int i = 0; i < 8; ++i) R.x[i] = d_in[1+i];
  R.W_i=d_in[9];  R.U_i=d_in[10]; R.b_i=d_in[11];
  R.W_f=d_in[12]; R.U_f=d_in[13]; R.b_f=d_in[14];
  R.W_c=d_in[15]; R.U_c=d_in[16]; R.b_c=d_in[17];
  R.W_o=d_in[18]; R.U_o=d_in[19]; R.b_o=d_in[20];
  R.W_ix=d_in[21]; R.U_ix=d_in[22]; R.b_ix=d_in[23];
  R.W_cx=d_in[24]; R.U_cx=d_in[25]; R.b_cx=d_in[26];
  R.W_a =d_in[27]; R.b_a =d_in[28];
  R.Ucat=(float*)(ws+OFF_UCAT); R.Wa=(float*)(ws+OFF_WA);
  R.Wm=(float*)(ws+OFF_WM); R.Wx=(float*)(ws+OFF_WX);
  R.Bm=(float*)(ws+OFF_BM); R.Bx=(float*)(ws+OFF_BX); R.Ba=(float*)(ws+OFF_BA);
  R.Yt=(float*)(ws+OFF_YT); R.Xt=(float*)(ws+OFF_XT);
  R.flag=(const unsigned*)(ws+OFF_FLAG);

  Params P;
  P.Ucat=R.Ucat; P.Wa=R.Wa; P.Wm=R.Wm; P.Wx=R.Wx;
  P.Bm=R.Bm; P.Bx=R.Bx; P.Ba=R.Ba; P.Yt=R.Yt; P.Xt=R.Xt;
  P.Hg=(float*)(ws+OFF_HG); P.Cg=(float*)(ws+OFF_CG); P.Gall=(float*)(ws+OFF_GALL);
  P.bar=(unsigned*)(ws+OFF_BAR);
  P.flag=R.flag;
  P.out=d_out;

  // zero barrier block + flag + Hg + Cg (ws is poisoned 0xAA before every call)
  hipMemsetAsync(d_ws, 0, OFF_GALL, stream);

  k_detect<<<1, 64, 0, stream>>>((const unsigned short*)d_in[10], (unsigned*)(ws+OFF_FLAG));
  k_conv_w <<<21899, 256, 0, stream>>>(R);
  k_conv_in<<<14336, 256, 0, stream>>>(R);

  const int smemBytes = L_TOT * 4;   // 152064 B < 160 KB/CU -> 1 WG/CU, 8 waves
  hipFuncSetAttribute((const void*)lstm_main,
                      hipFuncAttributeMaxDynamicSharedMemorySize, smemBytes);
  lstm_main<<<dim3(GRID), dim3(NTHR), smemBytes, stream>>>(P);
}